// Round 14
// baseline (648.011 us; speedup 1.0000x reference)
//
#include <hip/hip_runtime.h>
#include <hip/hip_bf16.h>
#include <math.h>

// SpatialGNN: B=64, N=1024 (32x32 grid), D_FEAT=1024, CTX=512, S=32, T=4
// Algebraic merge: x1 = elu( stencil(images) @ (W1·KB)^T + deg·(W1·kb_b + bias2[0]) )
#define NB 64
#define NNODES 1024
#define CTXD 512
#define SEQL 32

typedef __attribute__((ext_vector_type(8))) short short8;
typedef __attribute__((ext_vector_type(4))) short short4v;
typedef __attribute__((ext_vector_type(4))) float floatx4;

__device__ __forceinline__ float bf2f(unsigned short u) {
  union { unsigned int i; float f; } v; v.i = ((unsigned int)u) << 16; return v.f;
}
__device__ __forceinline__ unsigned short f2bf(float f) {
  union { float f; unsigned int i; } v; v.f = f;
  unsigned int r = v.i + 0x7fffu + ((v.i >> 16) & 1u);  // RNE
  return (unsigned short)(r >> 16);
}
__device__ __forceinline__ float elu1(float x) { return x > 0.f ? x : expm1f(x); }

__device__ __forceinline__ void gload16(const void* g, void* l) {
  __builtin_amdgcn_global_load_lds((const __attribute__((address_space(1))) void*)g,
                                   (__attribute__((address_space(3))) void*)l, 16, 0, 0);
}

// ---------------------------------------------------------------------------
// Pack: w1_bf + f32 TRANSPOSED cmd-path weights. 1835008 elems -> 7168 blocks.
// ---------------------------------------------------------------------------
__global__ __launch_bounds__(256) void pack_k(const float* __restrict__ Ww,
                                              const float* __restrict__ qiw,
                                              const float* __restrict__ qtw,
                                              unsigned short* __restrict__ w1_bf,
                                              float* __restrict__ qiT,
                                              float* __restrict__ qTT,
                                              float* __restrict__ w2T) {
  int idx = blockIdx.x * 256 + threadIdx.x;
  if (idx < 262144) {
    w1_bf[idx] = f2bf(Ww[(idx >> 9) * 1024 + (idx & 511)]);
  } else if (idx < 524288) {
    int o = idx - 262144;
    int k = o >> 9, c = o & 511;
    qiT[o] = qiw[c * 512 + k];
  } else if (idx < 1572864) {
    int o = idx - 524288;
    int t = o >> 18, r = o & 262143;
    int k = r >> 9, c = r & 511;
    qTT[o] = qtw[((size_t)t * 512 + c) * 512 + k];
  } else {
    int o = idx - 1572864;
    int k = o >> 9, c = o & 511;
    w2T[o] = Ww[c * 1024 + 512 + k];
  }
}

// ---------------------------------------------------------------------------
// M = W1[512,512] @ KB[512,1024] -> bf16 [512][1024]; block 128 = w1b (hidden
// under the other 128 blocks).  M[c',d] = sum_c W_w[c'*1024+c]*initKB_w[c*1024+d]
// ---------------------------------------------------------------------------
__global__ __launch_bounds__(256) void w1kb_k(const float* __restrict__ Ww,
                                              const float* __restrict__ kbw,
                                              const float* __restrict__ ikb_b,
                                              unsigned short* __restrict__ w1kb_bf,
                                              float* __restrict__ w1b) {
  int bi = blockIdx.x;
  int tid = threadIdx.x;
  if (bi == 128) {
    __shared__ float bs[512];
    bs[tid] = ikb_b[tid];
    bs[tid + 256] = ikb_b[tid + 256];
    __syncthreads();
#pragma unroll
    for (int rep = 0; rep < 2; rep++) {
      int c = tid + rep * 256;
      float s = 0.f;
      for (int k = 0; k < 512; k++) s += Ww[(size_t)c * 1024 + k] * bs[k];
      w1b[c] = s;
    }
    return;
  }
  __shared__ float ws1[4][512];
  int cb = bi * 4;
#pragma unroll
  for (int e = 0; e < 8; e++) {
    int o = e * 256 + tid;
    ws1[o >> 9][o & 511] = Ww[(size_t)(cb + (o >> 9)) * 1024 + (o & 511)];
  }
  __syncthreads();
  int d0 = tid * 4;
  floatx4 a0 = {0.f, 0.f, 0.f, 0.f}, a1 = a0, a2 = a0, a3 = a0;
  for (int c = 0; c < 512; c++) {
    floatx4 kb = *(const floatx4*)&kbw[(size_t)c * 1024 + d0];
    a0 += kb * ws1[0][c];
    a1 += kb * ws1[1][c];
    a2 += kb * ws1[2][c];
    a3 += kb * ws1[3][c];
  }
#pragma unroll
  for (int j = 0; j < 4; j++) {
    w1kb_bf[(size_t)(cb + 0) * 1024 + d0 + j] = f2bf(a0[j]);
    w1kb_bf[(size_t)(cb + 1) * 1024 + d0 + j] = f2bf(a1[j]);
    w1kb_bf[(size_t)(cb + 2) * 1024 + d0 + j] = f2bf(a2[j]);
    w1kb_bf[(size_t)(cb + 3) * 1024 + d0 + j] = f2bf(a3[j]);
  }
}

// ---------------------------------------------------------------------------
// q1[b][c] = elu(q_enc[b] @ qInput_w^T + qInput_b)
// ---------------------------------------------------------------------------
__global__ __launch_bounds__(512) void q1_k(const float* __restrict__ q_enc,
                                            const float* __restrict__ qiT,
                                            const float* __restrict__ qInput_b,
                                            float* __restrict__ q1) {
  int b = blockIdx.x, c = threadIdx.x;
  __shared__ float qes[512];
  qes[c] = q_enc[b * 512 + c];
  __syncthreads();
  float a0 = qInput_b[c], a1 = 0.f, a2 = 0.f, a3 = 0.f;
#pragma unroll 4
  for (int k = 0; k < 512; k += 4) {
    a0 += qes[k] * qiT[k * 512 + c];
    a1 += qes[k + 1] * qiT[(k + 1) * 512 + c];
    a2 += qes[k + 2] * qiT[(k + 2) * 512 + c];
    a3 += qes[k + 3] * qiT[(k + 3) * 512 + c];
  }
  q1[b * 512 + c] = elu1(a0 + a1 + a2 + a3);
}

// ---------------------------------------------------------------------------
// Per (t,b): q_cmd -> raw_att -> softmax -> cmd -> bias2[t][b][:]
// t==0 folds w1b (= W1 @ initKB_b) into bias2[0] for the merged init GEMM.
// ---------------------------------------------------------------------------
__global__ __launch_bounds__(512) void cmdt_k(
    const float* __restrict__ q1, const float* __restrict__ lstm,
    const int* __restrict__ q_len,
    const float* __restrict__ qTT, const float* __restrict__ qT_b,
    const float* __restrict__ cmd_w, const float* __restrict__ cmd_b,
    const float* __restrict__ w2T, const float* __restrict__ W_b,
    const float* __restrict__ w1b,
    float* __restrict__ bias2) {
  int b = blockIdx.x & 63;
  int t = blockIdx.x >> 6;
  int c = threadIdx.x;
  __shared__ float q1s[512];
  __shared__ float us[512];
  __shared__ float red[512];
  __shared__ float atts[32];
  __shared__ float cmds[512];

  q1s[c] = q1[b * 512 + c];
  __syncthreads();

  const float* wt = qTT + (size_t)t * 262144;
  float a0 = qT_b[t * 512 + c], a1 = 0.f, a2 = 0.f, a3 = 0.f;
#pragma unroll 4
  for (int k = 0; k < 512; k += 4) {
    a0 += q1s[k] * wt[k * 512 + c];
    a1 += q1s[k + 1] * wt[(k + 1) * 512 + c];
    a2 += q1s[k + 2] * wt[(k + 2) * 512 + c];
    a3 += q1s[k + 3] * wt[(k + 3) * 512 + c];
  }
  us[c] = (a0 + a1 + a2 + a3) * cmd_w[c];
  __syncthreads();

  const float* lstmb = lstm + (size_t)b * SEQL * 512;
  {
    int s = c >> 4, u = c & 15;
    float p = 0.f;
    const float* lr = lstmb + s * 512;
    for (int r = u; r < 512; r += 16) p += us[r] * lr[r];
    red[c] = p;
  }
  __syncthreads();
  if (c < 32) {
    float raw = cmd_b[0];
    for (int u = 0; u < 16; u++) raw += red[c * 16 + u];
    raw = (c < q_len[b]) ? raw : -1e30f;
    float mx = raw;
    for (int off = 16; off; off >>= 1) mx = fmaxf(mx, __shfl_xor(mx, off, 32));
    float e = expf(raw - mx);
    float sm = e;
    for (int off = 16; off; off >>= 1) sm += __shfl_xor(sm, off, 32);
    atts[c] = e / sm;
  }
  __syncthreads();
  float cd = 0.f;
#pragma unroll
  for (int s = 0; s < 32; s++) cd += atts[s] * lstmb[s * 512 + c];
  cmds[c] = cd;
  __syncthreads();

  float b0 = W_b[c], b1 = 0.f, b2 = 0.f, b3 = 0.f;
#pragma unroll 4
  for (int k = 0; k < 512; k += 4) {
    b0 += cmds[k] * w2T[k * 512 + c];
    b1 += cmds[k + 1] * w2T[(k + 1) * 512 + c];
    b2 += cmds[k + 2] * w2T[(k + 2) * 512 + c];
    b3 += cmds[k + 3] * w2T[(k + 3) * 512 + c];
  }
  float res = b0 + b1 + b2 + b3;
  if (t == 0) res += w1b[c];
  bias2[((size_t)(t * 64 + b)) * 512 + c] = res;
}

// ---------------------------------------------------------------------------
// f32 5-pt stencil on images -> bf16 S [65536][1024] (fills d_out exactly)
// ---------------------------------------------------------------------------
__global__ __launch_bounds__(256) void stencil_img_k(const float* __restrict__ img,
                                                     unsigned short* __restrict__ S) {
  int g = blockIdx.x * 256 + threadIdx.x;   // 16,777,216 float4-granules
  int v = g & 255;
  int n = (g >> 8) & 1023;
  int b = g >> 18;
  size_t base = (((size_t)b * 1024 + n) * 1024) + v * 4;
  const float* p = img + base;
  floatx4 s = *(const floatx4*)p;
  int i = n >> 5, j = n & 31;
  if (i > 0)  s += *(const floatx4*)(p - 32 * 1024);
  if (i < 31) s += *(const floatx4*)(p + 32 * 1024);
  if (j > 0)  s += *(const floatx4*)(p - 1024);
  if (j < 31) s += *(const floatx4*)(p + 1024);
  short4v o;
#pragma unroll
  for (int e = 0; e < 4; e++) o[e] = (short)f2bf(s[e]);
  *(short4v*)(S + base) = o;
}

// ---------------------------------------------------------------------------
// 5-point stencil: y[b,n,:] = sum_{m in nbr(n)} x[b,m,:]   (bf16, f32 sum)
// ---------------------------------------------------------------------------
__global__ __launch_bounds__(256) void stencil_k(const unsigned short* __restrict__ x,
                                                 unsigned short* __restrict__ y) {
  int g = blockIdx.x * 256 + threadIdx.x;
  int v = g & 63;
  int n = (g >> 6) & 1023;
  int b = g >> 16;
  size_t base = ((((size_t)b << 10) + n) << 9) + v * 8;
  const unsigned short* p = x + base;
  float acc[8];
  short8 s = *(const short8*)p;
#pragma unroll
  for (int j = 0; j < 8; j++) acc[j] = bf2f((unsigned short)s[j]);
  int i = n >> 5, jj = n & 31;
  if (i > 0) {
    short8 t = *(const short8*)(p - 32 * 512);
#pragma unroll
    for (int j = 0; j < 8; j++) acc[j] += bf2f((unsigned short)t[j]);
  }
  if (i < 31) {
    short8 t = *(const short8*)(p + 32 * 512);
#pragma unroll
    for (int j = 0; j < 8; j++) acc[j] += bf2f((unsigned short)t[j]);
  }
  if (jj > 0) {
    short8 t = *(const short8*)(p - 512);
#pragma unroll
    for (int j = 0; j < 8; j++) acc[j] += bf2f((unsigned short)t[j]);
  }
  if (jj < 31) {
    short8 t = *(const short8*)(p + 512);
#pragma unroll
    for (int j = 0; j < 8; j++) acc[j] += bf2f((unsigned short)t[j]);
  }
  short8 o;
#pragma unroll
  for (int j = 0; j < 8; j++) o[j] = (short)f2bf(acc[j]);
  *(short8*)(y + base) = o;
}

// ---------------------------------------------------------------------------
// 8-phase counted-vmcnt GEMM (round-9 proven schedule, generalized):
// 256x256 tile, 8 waves, BK=64, K = NT*64, A row stride LDA, B row stride LDB.
// MODE 1: +deg*bias2, elu, bf16 out.  MODE 2: +deg*bias2, no act, f32 out.
// vmcnt ledger is NT-independent (per-tile 4 stages x 2 loads; end-of-tile
// wait vmcnt(4) while t+2<NT else vmcnt(0)).
// ---------------------------------------------------------------------------
template <int MODE, int NT, int LDA, int LDB>
__global__ __launch_bounds__(512, 2) void gemm8(
    const unsigned short* __restrict__ Ay,
    const unsigned short* __restrict__ Bw,
    const float* __restrict__ bias2,
    void* __restrict__ Cp) {
  __shared__ __align__(128) unsigned short AsL[2][2][8192];  // 64 KB
  __shared__ __align__(128) unsigned short BsL[2][2][8192];  // 64 KB

  const int tid = threadIdx.x;
  const int lane = tid & 63;
  const int wave = tid >> 6;
  const int wm = wave >> 2;
  const int wn = wave & 3;
  const int lr = lane & 15;
  const int lk = lane >> 4;
  const int lr7 = lr & 7;
  const int rB0 = (wn & 1) * 64;

  int bid = blockIdx.x;
  int wg = (bid & 7) * (gridDim.x >> 3) + (bid >> 3);   // grid=512, %8==0
  const size_t rowBase = (size_t)(wg >> 1) * 256;
  const int colBase = (wg & 1) * 256;

  floatx4 acc[8][4];
#pragma unroll
  for (int m = 0; m < 8; m++)
#pragma unroll
    for (int n = 0; n < 4; n++) acc[m][n] = {0.f, 0.f, 0.f, 0.f};

  auto stgA = [&](int d, int h, int kt) {
#pragma unroll
    for (int j = 0; j < 2; j++) {
      int g = j * 512 + tid, r = g >> 3, u = g & 7;
      gload16(Ay + (rowBase + h * 128 + r) * (size_t)LDA + kt * 64 + ((u ^ (r & 7)) << 3),
              (char*)&AsL[d][h][0] + g * 16);
    }
  };
  auto stgB = [&](int d, int h, int kt) {
#pragma unroll
    for (int j = 0; j < 2; j++) {
      int g = j * 512 + tid, r = g >> 3, u = g & 7;
      gload16(Bw + (size_t)(colBase + h * 128 + r) * LDB + kt * 64 + ((u ^ (r & 7)) << 3),
              (char*)&BsL[d][h][0] + g * 16);
    }
  };

  // prologue
  stgB(0, 0, 0); stgA(0, 0, 0); stgA(0, 1, 0); stgB(0, 1, 0);
  stgB(1, 0, 1); stgA(1, 0, 1);
  asm volatile("s_waitcnt vmcnt(4)" ::: "memory");  // tile 0 landed
  __builtin_amdgcn_sched_barrier(0);
  __builtin_amdgcn_s_barrier();
  __builtin_amdgcn_sched_barrier(0);

  short8 a[2][4], b[2][4];

  for (int t = 0; t < NT; t++) {
    const int d = t & 1;
    const char* Ah = (const char*)&AsL[d][wm][0];
    const char* Bh = (const char*)&BsL[d][wn >> 1][0];

    // ---- P1 ----------------------------------------------------------------
#pragma unroll
    for (int kk = 0; kk < 2; kk++) {
      const int ub = ((kk << 2) + lk) ^ lr7;
#pragma unroll
      for (int m = 0; m < 4; m++)
        a[kk][m] = *(const short8*)(Ah + (m * 16 + lr) * 128 + (ub << 4));
#pragma unroll
      for (int n = 0; n < 2; n++)
        b[kk][n] = *(const short8*)(Bh + (rB0 + n * 16 + lr) * 128 + (ub << 4));
    }
    if (t + 1 < NT) stgA(d ^ 1, 1, t + 1);
    __builtin_amdgcn_sched_barrier(0);
    __builtin_amdgcn_s_barrier();
    asm volatile("s_waitcnt lgkmcnt(0)" ::: "memory");
    __builtin_amdgcn_sched_barrier(0);
    __builtin_amdgcn_s_setprio(1);
#pragma unroll
    for (int kk = 0; kk < 2; kk++)
#pragma unroll
      for (int m = 0; m < 4; m++)
#pragma unroll
        for (int n = 0; n < 2; n++)
          acc[m][n] = __builtin_amdgcn_mfma_f32_16x16x32_bf16(a[kk][m], b[kk][n], acc[m][n], 0, 0, 0);
    __builtin_amdgcn_s_setprio(0);
    __builtin_amdgcn_sched_barrier(0);
    __builtin_amdgcn_s_barrier();
    __builtin_amdgcn_sched_barrier(0);

    // ---- P2 ----------------------------------------------------------------
#pragma unroll
    for (int kk = 0; kk < 2; kk++) {
      const int ub = ((kk << 2) + lk) ^ lr7;
#pragma unroll
      for (int n = 2; n < 4; n++)
        b[kk][n] = *(const short8*)(Bh + (rB0 + n * 16 + lr) * 128 + (ub << 4));
    }
    if (t + 1 < NT) stgB(d ^ 1, 1, t + 1);
    __builtin_amdgcn_sched_barrier(0);
    __builtin_amdgcn_s_barrier();
    asm volatile("s_waitcnt lgkmcnt(0)" ::: "memory");
    __builtin_amdgcn_sched_barrier(0);
    __builtin_amdgcn_s_setprio(1);
#pragma unroll
    for (int kk = 0; kk < 2; kk++)
#pragma unroll
      for (int m = 0; m < 4; m++)
#pragma unroll
        for (int n = 2; n < 4; n++)
          acc[m][n] = __builtin_amdgcn_mfma_f32_16x16x32_bf16(a[kk][m], b[kk][n], acc[m][n], 0, 0, 0);
    __builtin_amdgcn_s_setprio(0);
    __builtin_amdgcn_sched_barrier(0);
    __builtin_amdgcn_s_barrier();
    __builtin_amdgcn_sched_barrier(0);

    // ---- P3 ----------------------------------------------------------------
#pragma unroll
    for (int kk = 0; kk < 2; kk++) {
      const int ub = ((kk << 2) + lk) ^ lr7;
#pragma unroll
      for (int m = 0; m < 4; m++)
        a[kk][m] = *(const short8*)(Ah + (64 + m * 16 + lr) * 128 + (ub << 4));
    }
    if (t + 2 < NT) stgB(d, 0, t + 2);
    __builtin_amdgcn_sched_barrier(0);
    __builtin_amdgcn_s_barrier();
    asm volatile("s_waitcnt lgkmcnt(0)" ::: "memory");
    __builtin_amdgcn_sched_barrier(0);
    __builtin_amdgcn_s_setprio(1);
#pragma unroll
    for (int kk = 0; kk < 2; kk++)
#pragma unroll
      for (int m = 0; m < 4; m++)
#pragma unroll
        for (int n = 0; n < 2; n++)
          acc[m + 4][n] = __builtin_amdgcn_mfma_f32_16x16x32_bf16(a[kk][m], b[kk][n], acc[m + 4][n], 0, 0, 0);
    __builtin_amdgcn_s_setprio(0);
    __builtin_amdgcn_sched_barrier(0);
    __builtin_amdgcn_s_barrier();
    __builtin_amdgcn_sched_barrier(0);

    // ---- P4 ----------------------------------------------------------------
    if (t + 2 < NT) stgA(d, 0, t + 2);
    __builtin_amdgcn_sched_barrier(0);
    __builtin_amdgcn_s_setprio(1);
#pragma unroll
    for (int kk = 0; kk < 2; kk++)
#pragma unroll
      for (int m = 0; m < 4; m++)
#pragma unroll
        for (int n = 2; n < 4; n++)
          acc[m + 4][n] = __builtin_amdgcn_mfma_f32_16x16x32_bf16(a[kk][m], b[kk][n], acc[m + 4][n], 0, 0, 0);
    __builtin_amdgcn_s_setprio(0);
    __builtin_amdgcn_sched_barrier(0);
    if (t + 2 < NT) {
      asm volatile("s_waitcnt vmcnt(4)" ::: "memory");  // tile t+1 landed
    } else {
      asm volatile("s_waitcnt vmcnt(0)" ::: "memory");
    }
    __builtin_amdgcn_sched_barrier(0);
    __builtin_amdgcn_s_barrier();
    __builtin_amdgcn_sched_barrier(0);
  }

  // Epilogue: C/D layout col=lane&15, row=(lane>>4)*4+reg [m89]
#pragma unroll
  for (int m = 0; m < 8; m++) {
#pragma unroll
    for (int q = 0; q < 4; q++) {
      size_t grow = rowBase + wm * 128 + m * 16 + lk * 4 + q;
      int nsp = (int)(grow & 1023);
      int ii = nsp >> 5, jj = nsp & 31;
      float degf = (float)(1 + (ii > 0) + (ii < 31) + (jj > 0) + (jj < 31));
      const float* b2 = bias2 + (grow >> 10) * CTXD;
#pragma unroll
      for (int n = 0; n < 4; n++) {
        int gcol = colBase + wn * 64 + n * 16 + lr;
        float v = acc[m][n][q] + degf * b2[gcol];
        if constexpr (MODE == 1) {
          ((unsigned short*)Cp)[grow * CTXD + gcol] = f2bf(elu1(v));
        } else {
          ((float*)Cp)[grow * CTXD + gcol] = v;
        }
      }
    }
  }
}

// ---------------------------------------------------------------------------
// Fused stencil+GEMM (round-10 verified): used only for t=3 (no Y buffer ->
// no d_out read/write race). 128x256 tile, 8 waves, counted-vmcnt pipeline.
// ---------------------------------------------------------------------------
struct Taps { short8 c, up, dn, lf, rt; };

template <int MODE>
__global__ __launch_bounds__(512, 2) void fgemm(
    const unsigned short* __restrict__ X,
    const unsigned short* __restrict__ Bw,
    const float* __restrict__ bias2,
    void* __restrict__ Cp) {
  __shared__ __align__(128) unsigned short AsL[2][128 * 64];
  __shared__ __align__(128) unsigned short BsL[2][256 * 64];

  const int tid = threadIdx.x;
  const int lane = tid & 63;
  const int wave = tid >> 6;
  const int wm = wave >> 2;
  const int wn = wave & 3;
  const int lr = lane & 15;
  const int lk = lane >> 4;
  const int lr7 = lr & 7;

  int bid = blockIdx.x;
  int wg = (bid & 7) * (gridDim.x >> 3) + (bid >> 3);   // grid=1024, %8==0
  const size_t rowBase = (size_t)(wg >> 1) * 128;
  const int colBase = (wg & 1) * 256;

  floatx4 acc[4][4];
#pragma unroll
  for (int m = 0; m < 4; m++)
#pragma unroll
    for (int n = 0; n < 4; n++) acc[m][n] = {0.f, 0.f, 0.f, 0.f};

  const int rl = tid >> 3;
  const int uu = tid & 7;

  auto issueT = [&](Taps& T, int h, int kt) {
    size_t R = rowBase + h * 64 + rl;
    int n = (int)(R & 1023);
    const unsigned short* p = X + R * 512 + kt * 64 + uu * 8;
    T.c = *(const short8*)p;
    T.up = *(const short8*)(p + (((n >> 5) > 0) ? -32 * 512 : 0));
    T.dn = *(const short8*)(p + (((n >> 5) < 31) ? 32 * 512 : 0));
    T.lf = *(const short8*)(p + (((n & 31) > 0) ? -512 : 0));
    T.rt = *(const short8*)(p + (((n & 31) < 31) ? 512 : 0));
  };
  auto commitT = [&](const Taps& T, int h, int d) {
    int r = h * 64 + rl;
    size_t R = rowBase + r;
    int n = (int)(R & 1023);
    float mu = ((n >> 5) > 0) ? 1.f : 0.f;
    float md = ((n >> 5) < 31) ? 1.f : 0.f;
    float ml = ((n & 31) > 0) ? 1.f : 0.f;
    float mr = ((n & 31) < 31) ? 1.f : 0.f;
    short8 o;
#pragma unroll
    for (int e = 0; e < 8; e++) {
      float s = bf2f((unsigned short)T.c[e]);
      s += mu * bf2f((unsigned short)T.up[e]);
      s += md * bf2f((unsigned short)T.dn[e]);
      s += ml * bf2f((unsigned short)T.lf[e]);
      s += mr * bf2f((unsigned short)T.rt[e]);
      o[e] = (short)f2bf(s);
    }
    *(short8*)((char*)&AsL[d][0] + r * 128 + ((uu ^ (r & 7)) << 4)) = o;
  };
  auto stgB = [&](int d, int h, int kt) {
#pragma unroll
    for (int j = 0; j < 2; j++) {
      int g = h * 1024 + j * 512 + tid;
      int r = g >> 3, u = g & 7;
      gload16(Bw + (size_t)(colBase + r) * 512 + kt * 64 + ((u ^ (r & 7)) << 3),
              (char*)&BsL[d][0] + g * 16);
    }
  };
  auto phase = [&](int d, int kk) {
    const char* Ab = (const char*)&AsL[d][0];
    const char* Bb = (const char*)&BsL[d][0];
    const int ub = ((kk << 2) + lk) ^ lr7;
    short8 a[4], b[4];
#pragma unroll
    for (int m = 0; m < 4; m++)
      a[m] = *(const short8*)(Ab + (wm * 64 + m * 16 + lr) * 128 + (ub << 4));
#pragma unroll
    for (int n = 0; n < 4; n++)
      b[n] = *(const short8*)(Bb + (wn * 64 + n * 16 + lr) * 128 + (ub << 4));
    asm volatile("s_waitcnt lgkmcnt(0)" ::: "memory");
    __builtin_amdgcn_sched_barrier(0);
    __builtin_amdgcn_s_setprio(1);
#pragma unroll
    for (int m = 0; m < 4; m++)
#pragma unroll
      for (int n = 0; n < 4; n++)
        acc[m][n] = __builtin_amdgcn_mfma_f32_16x16x32_bf16(a[m], b[n], acc[m][n], 0, 0, 0);
    __builtin_amdgcn_s_setprio(0);
    __builtin_amdgcn_sched_barrier(0);
  };

  Taps tH0, tH1;

  issueT(tH0, 0, 0);
  issueT(tH1, 1, 0);
  __builtin_amdgcn_sched_barrier(0);
  stgB(0, 0, 0);
  stgB(0, 1, 0);
  __builtin_amdgcn_sched_barrier(0);
  asm volatile("s_waitcnt vmcnt(9)" ::: "memory");
  __builtin_amdgcn_sched_barrier(0);
  commitT(tH0, 0, 0);
  asm volatile("s_waitcnt vmcnt(4)" ::: "memory");
  __builtin_amdgcn_sched_barrier(0);
  commitT(tH1, 1, 0);
  issueT(tH0, 0, 1);
  issueT(tH1, 1, 1);
  __builtin_amdgcn_sched_barrier(0);
  asm volatile("s_waitcnt vmcnt(10)" ::: "memory");
  asm volatile("s_waitcnt lgkmcnt(0)" ::: "memory");
  __builtin_amdgcn_sched_barrier(0);
  __builtin_amdgcn_s_barrier();
  __builtin_amdgcn_sched_barrier(0);

  for (int t = 0; t < 8; t++) {
    const int cur = t & 1, nxt = cur ^ 1;
    const int ktn = (t + 1) & 7, kt2 = (t + 2) & 7;

    stgB(nxt, 0, ktn);
    __builtin_amdgcn_sched_barrier(0);
    phase(cur, 0);
    asm volatile("s_waitcnt vmcnt(7)" ::: "memory");
    __builtin_amdgcn_sched_barrier(0);
    commitT(tH0, 0, nxt);
    __builtin_amdgcn_sched_barrier(0);

    stgB(nxt, 1, ktn);
    __builtin_amdgcn_sched_barrier(0);
    phase(cur, 1);
    asm volatile("s_waitcnt vmcnt(4)" ::: "memory");
    __builtin_amdgcn_sched_barrier(0);
    commitT(tH1, 1, nxt);
    issueT(tH0, 0, kt2);
    issueT(tH1, 1, kt2);
    __builtin_amdgcn_sched_barrier(0);
    asm volatile("s_waitcnt vmcnt(10)" ::: "memory");
    asm volatile("s_waitcnt lgkmcnt(0)" ::: "memory");
    __builtin_amdgcn_sched_barrier(0);
    __builtin_amdgcn_s_barrier();
    __builtin_amdgcn_sched_barrier(0);
  }
  asm volatile("s_waitcnt vmcnt(0)" ::: "memory");

#pragma unroll
  for (int m = 0; m < 4; m++) {
#pragma unroll
    for (int q = 0; q < 4; q++) {
      size_t grow = rowBase + wm * 64 + m * 16 + lk * 4 + q;
      int nsp = (int)(grow & 1023);
      int ii = nsp >> 5, jj = nsp & 31;
      float degf = (float)(1 + (ii > 0) + (ii < 31) + (jj > 0) + (jj < 31));
      const float* b2 = bias2 + (grow >> 10) * CTXD;
#pragma unroll
      for (int n = 0; n < 4; n++) {
        int gcol = colBase + wn * 64 + n * 16 + lr;
        float v = acc[m][n][q] + degf * b2[gcol];
        if constexpr (MODE == 1) {
          ((unsigned short*)Cp)[grow * CTXD + gcol] = f2bf(elu1(v));
        } else {
          ((float*)Cp)[grow * CTXD + gcol] = v;
        }
      }
    }
  }
}

// ---------------------------------------------------------------------------
extern "C" void kernel_launch(void* const* d_in, const int* in_sizes, int n_in,
                              void* d_out, int out_size, void* d_ws, size_t ws_size,
                              hipStream_t stream) {
  const float* images   = (const float*)d_in[0];
  const float* q_enc    = (const float*)d_in[1];
  const float* lstm     = (const float*)d_in[2];
  const int*   q_len    = (const int*)d_in[3];
  // d_in[4] = adj: implied by the 32x32 grid stencil, not read
  const float* initKB_w = (const float*)d_in[5];
  const float* initKB_b = (const float*)d_in[6];
  const float* W_w      = (const float*)d_in[7];
  const float* W_b      = (const float*)d_in[8];
  const float* qInput_w = (const float*)d_in[9];
  const float* qInput_b = (const float*)d_in[10];
  const float* qT_w     = (const float*)d_in[11];
  const float* qT_b     = (const float*)d_in[12];
  const float* cmd_w    = (const float*)d_in[13];
  const float* cmd_b    = (const float*)d_in[14];

  // ws layout:
  //   X (bf16 state buffer): 64 MB   (transposed cmd weights aliased at front
  //        6 MB — consumed by q1_k/cmdt_k before the merged GEMM writes X)
  //   w1kb_bf(1MB) / w1_bf(512KB) / bias2(512KB) / q1(128KB) / w1b(2KB)
  char* ws = (char*)d_ws;
  unsigned short* X       = (unsigned short*)ws;
  float*          qiT     = (float*)ws;                    // 1 MB
  float*          qTT     = (float*)(ws + 1048576);        // 4 MB
  float*          w2T     = (float*)(ws + 5242880);        // 1 MB
  unsigned short* w1kb_bf = (unsigned short*)(ws + 67108864);
  unsigned short* w1_bf   = (unsigned short*)(ws + 68157440);
  float*          bias2   = (float*)(ws + 68681728);
  float*          q1      = (float*)(ws + 69206016);
  float*          w1b     = (float*)(ws + 69337088);
  // d_out (134 MB) holds: S = stencil(images) bf16 [65536][1024] (exact fit),
  // later Y = stencil(x) bf16 [65536][512] (first 64 MB), finally f32 output.
  unsigned short* S       = (unsigned short*)d_out;
  unsigned short* Y       = (unsigned short*)d_out;

  pack_k<<<7168, 256, 0, stream>>>(W_w, qInput_w, qT_w, w1_bf, qiT, qTT, w2T);
  w1kb_k<<<129, 256, 0, stream>>>(W_w, initKB_w, initKB_b, w1kb_bf, w1b);
  q1_k<<<64, 512, 0, stream>>>(q_enc, qiT, qInput_b, q1);
  cmdt_k<<<256, 512, 0, stream>>>(q1, lstm, q_len, qTT, qT_b, cmd_w, cmd_b,
                                  w2T, W_b, w1b, bias2);

  // S = stencil(images) -> bf16 (fills d_out)
  stencil_img_k<<<65536, 256, 0, stream>>>(images, S);

  // Merged t=0: X1 = elu( S @ (W1·KB)^T + deg·(bias2[0]+w1b) )
  gemm8<1, 16, 1024, 1024><<<512, 512, 0, stream>>>(S, w1kb_bf, bias2, X);

  // t=1,2: stencil + GEMM (X ws <-> Y d_out; S dead after merged GEMM)
  stencil_k<<<16384, 256, 0, stream>>>(X, Y);
  gemm8<1, 8, 512, 512><<<512, 512, 0, stream>>>(Y, w1_bf, bias2 + 32768, X);
  stencil_k<<<16384, 256, 0, stream>>>(X, Y);
  gemm8<1, 8, 512, 512><<<512, 512, 0, stream>>>(Y, w1_bf, bias2 + 2 * 32768, X);

  // t=3: fused stencil+GEMM (reads X in ws, writes f32 d_out — no race)
  fgemm<2><<<1024, 512, 0, stream>>>(X, w1_bf, bias2 + 3 * 32768, d_out);
}

// Round 15
// 525.876 us; speedup vs baseline: 1.2323x; 1.2323x over previous
//
#include <hip/hip_runtime.h>
#include <hip/hip_bf16.h>
#include <math.h>

// SpatialGNN: B=64, N=1024 (32x32 grid), D_FEAT=1024, CTX=512, S=32, T=4
#define NB 64
#define NNODES 1024
#define CTXD 512
#define SEQL 32

typedef __attribute__((ext_vector_type(8))) short short8;
typedef __attribute__((ext_vector_type(4))) float floatx4;

__device__ __forceinline__ float bf2f(unsigned short u) {
  union { unsigned int i; float f; } v; v.i = ((unsigned int)u) << 16; return v.f;
}
__device__ __forceinline__ unsigned short f2bf(float f) {
  union { float f; unsigned int i; } v; v.f = f;
  unsigned int r = v.i + 0x7fffu + ((v.i >> 16) & 1u);  // RNE
  return (unsigned short)(r >> 16);
}
__device__ __forceinline__ float elu1(float x) { return x > 0.f ? x : expm1f(x); }

__device__ __forceinline__ void gload16(const void* g, void* l) {
  __builtin_amdgcn_global_load_lds((const __attribute__((address_space(1))) void*)g,
                                   (__attribute__((address_space(3))) void*)l, 16, 0, 0);
}

// ---------------------------------------------------------------------------
// Pack: bf16 GEMM weights + f32 TRANSPOSED cmd-path weights.
// ---------------------------------------------------------------------------
__global__ __launch_bounds__(256) void pack_k(const float* __restrict__ kbw,
                                              const float* __restrict__ Ww,
                                              const float* __restrict__ qiw,
                                              const float* __restrict__ qtw,
                                              unsigned short* __restrict__ kb_bf,
                                              unsigned short* __restrict__ w1_bf,
                                              float* __restrict__ qiT,
                                              float* __restrict__ qTT,
                                              float* __restrict__ w2T) {
  int idx = blockIdx.x * 256 + threadIdx.x;
  if (idx < 524288) {
    kb_bf[idx] = f2bf(kbw[idx]);
  } else if (idx < 786432) {
    int o = idx - 524288;
    w1_bf[o] = f2bf(Ww[(o >> 9) * 1024 + (o & 511)]);
  } else if (idx < 1048576) {
    int o = idx - 786432;
    int k = o >> 9, c = o & 511;
    qiT[o] = qiw[c * 512 + k];
  } else if (idx < 2097152) {
    int o = idx - 1048576;
    int t = o >> 18, r = o & 262143;
    int k = r >> 9, c = r & 511;
    qTT[o] = qtw[((size_t)t * 512 + c) * 512 + k];
  } else {
    int o = idx - 2097152;
    int k = o >> 9, c = o & 511;
    w2T[o] = Ww[c * 1024 + 512 + k];
  }
}

// ---------------------------------------------------------------------------
// q1[b][c] = elu(q_enc[b] @ qInput_w^T + qInput_b)
// ---------------------------------------------------------------------------
__global__ __launch_bounds__(512) void q1_k(const float* __restrict__ q_enc,
                                            const float* __restrict__ qiT,
                                            const float* __restrict__ qInput_b,
                                            float* __restrict__ q1) {
  int b = blockIdx.x, c = threadIdx.x;
  __shared__ float qes[512];
  qes[c] = q_enc[b * 512 + c];
  __syncthreads();
  float a0 = qInput_b[c], a1 = 0.f, a2 = 0.f, a3 = 0.f;
#pragma unroll 4
  for (int k = 0; k < 512; k += 4) {
    a0 += qes[k] * qiT[k * 512 + c];
    a1 += qes[k + 1] * qiT[(k + 1) * 512 + c];
    a2 += qes[k + 2] * qiT[(k + 2) * 512 + c];
    a3 += qes[k + 3] * qiT[(k + 3) * 512 + c];
  }
  q1[b * 512 + c] = elu1(a0 + a1 + a2 + a3);
}

// ---------------------------------------------------------------------------
// Per (t,b): q_cmd -> raw_att -> softmax -> cmd -> bias2[t][b][:]
// ---------------------------------------------------------------------------
__global__ __launch_bounds__(512) void cmdt_k(
    const float* __restrict__ q1, const float* __restrict__ lstm,
    const int* __restrict__ q_len,
    const float* __restrict__ qTT, const float* __restrict__ qT_b,
    const float* __restrict__ cmd_w, const float* __restrict__ cmd_b,
    const float* __restrict__ w2T, const float* __restrict__ W_b,
    float* __restrict__ bias2) {
  int b = blockIdx.x & 63;
  int t = blockIdx.x >> 6;
  int c = threadIdx.x;
  __shared__ float q1s[512];
  __shared__ float us[512];
  __shared__ float red[512];
  __shared__ float atts[32];
  __shared__ float cmds[512];

  q1s[c] = q1[b * 512 + c];
  __syncthreads();

  const float* wt = qTT + (size_t)t * 262144;
  float a0 = qT_b[t * 512 + c], a1 = 0.f, a2 = 0.f, a3 = 0.f;
#pragma unroll 4
  for (int k = 0; k < 512; k += 4) {
    a0 += q1s[k] * wt[k * 512 + c];
    a1 += q1s[k + 1] * wt[(k + 1) * 512 + c];
    a2 += q1s[k + 2] * wt[(k + 2) * 512 + c];
    a3 += q1s[k + 3] * wt[(k + 3) * 512 + c];
  }
  us[c] = (a0 + a1 + a2 + a3) * cmd_w[c];
  __syncthreads();

  const float* lstmb = lstm + (size_t)b * SEQL * 512;
  {
    int s = c >> 4, u = c & 15;
    float p = 0.f;
    const float* lr = lstmb + s * 512;
    for (int r = u; r < 512; r += 16) p += us[r] * lr[r];
    red[c] = p;
  }
  __syncthreads();
  if (c < 32) {
    float raw = cmd_b[0];
    for (int u = 0; u < 16; u++) raw += red[c * 16 + u];
    raw = (c < q_len[b]) ? raw : -1e30f;
    float mx = raw;
    for (int off = 16; off; off >>= 1) mx = fmaxf(mx, __shfl_xor(mx, off, 32));
    float e = expf(raw - mx);
    float sm = e;
    for (int off = 16; off; off >>= 1) sm += __shfl_xor(sm, off, 32);
    atts[c] = e / sm;
  }
  __syncthreads();
  float cd = 0.f;
#pragma unroll
  for (int s = 0; s < 32; s++) cd += atts[s] * lstmb[s * 512 + c];
  cmds[c] = cd;
  __syncthreads();

  float b0 = W_b[c], b1 = 0.f, b2 = 0.f, b3 = 0.f;
#pragma unroll 4
  for (int k = 0; k < 512; k += 4) {
    b0 += cmds[k] * w2T[k * 512 + c];
    b1 += cmds[k + 1] * w2T[(k + 1) * 512 + c];
    b2 += cmds[k + 2] * w2T[(k + 2) * 512 + c];
    b3 += cmds[k + 3] * w2T[(k + 3) * 512 + c];
  }
  bias2[((size_t)(t * 64 + b)) * 512 + c] = b0 + b1 + b2 + b3;
}

// ---------------------------------------------------------------------------
// 5-point stencil: y[b,n,:] = sum_{m in nbr(n)} x[b,m,:]   (bf16, f32 sum)
// ---------------------------------------------------------------------------
__global__ __launch_bounds__(256) void stencil_k(const unsigned short* __restrict__ x,
                                                 unsigned short* __restrict__ y) {
  int g = blockIdx.x * 256 + threadIdx.x;
  int v = g & 63;
  int n = (g >> 6) & 1023;
  int b = g >> 16;
  size_t base = ((((size_t)b << 10) + n) << 9) + v * 8;
  const unsigned short* p = x + base;
  float acc[8];
  short8 s = *(const short8*)p;
#pragma unroll
  for (int j = 0; j < 8; j++) acc[j] = bf2f((unsigned short)s[j]);
  int i = n >> 5, jj = n & 31;
  if (i > 0) {
    short8 t = *(const short8*)(p - 32 * 512);
#pragma unroll
    for (int j = 0; j < 8; j++) acc[j] += bf2f((unsigned short)t[j]);
  }
  if (i < 31) {
    short8 t = *(const short8*)(p + 32 * 512);
#pragma unroll
    for (int j = 0; j < 8; j++) acc[j] += bf2f((unsigned short)t[j]);
  }
  if (jj > 0) {
    short8 t = *(const short8*)(p - 512);
#pragma unroll
    for (int j = 0; j < 8; j++) acc[j] += bf2f((unsigned short)t[j]);
  }
  if (jj < 31) {
    short8 t = *(const short8*)(p + 512);
#pragma unroll
    for (int j = 0; j < 8; j++) acc[j] += bf2f((unsigned short)t[j]);
  }
  short8 o;
#pragma unroll
  for (int j = 0; j < 8; j++) o[j] = (short)f2bf(acc[j]);
  *(short8*)(y + base) = o;
}

// ---------------------------------------------------------------------------
// Init GEMM: 64x256 tile, 4 waves, BK=64, A=f32 reg-staged+cvt once,
// B gload_lds, XOR swizzle (0 conflicts measured). Round-9 proven form.
// ---------------------------------------------------------------------------
__global__ __launch_bounds__(256, 3) void igemm(
    const float* __restrict__ Af,
    const unsigned short* __restrict__ Bw,
    const float* __restrict__ cbias,
    unsigned short* __restrict__ Cp) {
  __shared__ __align__(128) unsigned short As[64 * 64];
  __shared__ __align__(128) unsigned short Bs[256 * 64];

  const int tid = threadIdx.x;
  const int lane = tid & 63;
  const int wn = tid >> 6;
  const int lr = lane & 15;
  const int lk = lane >> 4;
  const int lr7 = lr & 7;

  int bid = blockIdx.x;
  int wg = (bid & 7) * (gridDim.x >> 3) + (bid >> 3);
  const size_t rowBase = (size_t)(wg >> 1) * 64;
  const int colBase = (wg & 1) * 256;

  floatx4 acc[4][4];
#pragma unroll
  for (int m = 0; m < 4; m++)
#pragma unroll
    for (int n = 0; n < 4; n++) acc[m][n] = {0.f, 0.f, 0.f, 0.f};

  for (int k0 = 0; k0 < 1024; k0 += 64) {
    __syncthreads();
#pragma unroll
    for (int j = 0; j < 2; j++) {
      int g = j * 256 + tid;
      int r = g >> 3, u = g & 7;
      const float* src = Af + (rowBase + r) * (size_t)1024 + k0 + u * 8;
      floatx4 v0 = *(const floatx4*)src;
      floatx4 v1 = *(const floatx4*)(src + 4);
      short8 t;
#pragma unroll
      for (int e = 0; e < 4; e++) {
        t[e] = (short)f2bf(v0[e]);
        t[e + 4] = (short)f2bf(v1[e]);
      }
      *(short8*)((char*)As + r * 128 + ((u ^ (r & 7)) << 4)) = t;
    }
#pragma unroll
    for (int j = 0; j < 8; j++) {
      int g = j * 256 + tid;
      int r = g >> 3, u = g & 7;
      gload16(Bw + (size_t)(colBase + r) * 1024 + k0 + ((u ^ (r & 7)) << 3),
              (char*)Bs + g * 16);
    }
    __syncthreads();

#pragma unroll
    for (int kk = 0; kk < 2; kk++) {
      const int ub = ((kk << 2) + lk) ^ lr7;
      short8 a[4], b[4];
#pragma unroll
      for (int m = 0; m < 4; m++)
        a[m] = *(const short8*)((const char*)As + (m * 16 + lr) * 128 + (ub << 4));
#pragma unroll
      for (int n = 0; n < 4; n++)
        b[n] = *(const short8*)((const char*)Bs + (wn * 64 + n * 16 + lr) * 128 + (ub << 4));
#pragma unroll
      for (int m = 0; m < 4; m++)
#pragma unroll
        for (int n = 0; n < 4; n++)
          acc[m][n] = __builtin_amdgcn_mfma_f32_16x16x32_bf16(a[m], b[n], acc[m][n], 0, 0, 0);
    }
  }

#pragma unroll
  for (int m = 0; m < 4; m++) {
#pragma unroll
    for (int q = 0; q < 4; q++) {
      size_t grow = rowBase + m * 16 + lk * 4 + q;
#pragma unroll
      for (int n = 0; n < 4; n++) {
        int gcol = colBase + wn * 64 + n * 16 + lr;
        Cp[grow * CTXD + gcol] = f2bf(acc[m][n][q] + cbias[gcol]);
      }
    }
  }
}

// ---------------------------------------------------------------------------
// Loop GEMM, 8-phase counted-vmcnt schedule (round-9 proven):
// 256x256 tile, 8 waves (2M x 4N, wave out 128x64), BK=64, K=512 (NT=8).
// MODE 1: +deg*bias2, elu, bf16 out.  MODE 2: +deg*bias2, no act, f32 out.
// ---------------------------------------------------------------------------
template <int MODE>
__global__ __launch_bounds__(512, 2) void gemm8(
    const unsigned short* __restrict__ Ay,
    const unsigned short* __restrict__ Bw,
    const float* __restrict__ bias2,
    void* __restrict__ Cp) {
  __shared__ __align__(128) unsigned short AsL[2][2][8192];  // 64 KB
  __shared__ __align__(128) unsigned short BsL[2][2][8192];  // 64 KB

  const int tid = threadIdx.x;
  const int lane = tid & 63;
  const int wave = tid >> 6;       // 0..7
  const int wm = wave >> 2;        // 0..1  -> A half = wm
  const int wn = wave & 3;         // 0..3  -> B half = wn>>1
  const int lr = lane & 15;
  const int lk = lane >> 4;
  const int lr7 = lr & 7;
  const int rB0 = (wn & 1) * 64;

  int bid = blockIdx.x;
  int wg = (bid & 7) * (gridDim.x >> 3) + (bid >> 3);   // grid=512, %8==0
  const size_t rowBase = (size_t)(wg >> 1) * 256;
  const int colBase = (wg & 1) * 256;

  floatx4 acc[8][4];
#pragma unroll
  for (int m = 0; m < 8; m++)
#pragma unroll
    for (int n = 0; n < 4; n++) acc[m][n] = {0.f, 0.f, 0.f, 0.f};

  auto stgA = [&](int d, int h, int kt) {
#pragma unroll
    for (int j = 0; j < 2; j++) {
      int g = j * 512 + tid, r = g >> 3, u = g & 7;
      gload16(Ay + (rowBase + h * 128 + r) * (size_t)512 + kt * 64 + ((u ^ (r & 7)) << 3),
              (char*)&AsL[d][h][0] + g * 16);
    }
  };
  auto stgB = [&](int d, int h, int kt) {
#pragma unroll
    for (int j = 0; j < 2; j++) {
      int g = j * 512 + tid, r = g >> 3, u = g & 7;
      gload16(Bw + (size_t)(colBase + h * 128 + r) * 512 + kt * 64 + ((u ^ (r & 7)) << 3),
              (char*)&BsL[d][h][0] + g * 16);
    }
  };

  // prologue
  stgB(0, 0, 0); stgA(0, 0, 0); stgA(0, 1, 0); stgB(0, 1, 0);
  stgB(1, 0, 1); stgA(1, 0, 1);
  asm volatile("s_waitcnt vmcnt(4)" ::: "memory");  // tile 0 landed
  __builtin_amdgcn_sched_barrier(0);
  __builtin_amdgcn_s_barrier();
  __builtin_amdgcn_sched_barrier(0);

  short8 a[2][4], b[2][4];

  for (int t = 0; t < 8; t++) {
    const int d = t & 1;
    const char* Ah = (const char*)&AsL[d][wm][0];
    const char* Bh = (const char*)&BsL[d][wn >> 1][0];

    // ---- P1 ----------------------------------------------------------------
#pragma unroll
    for (int kk = 0; kk < 2; kk++) {
      const int ub = ((kk << 2) + lk) ^ lr7;
#pragma unroll
      for (int m = 0; m < 4; m++)
        a[kk][m] = *(const short8*)(Ah + (m * 16 + lr) * 128 + (ub << 4));
#pragma unroll
      for (int n = 0; n < 2; n++)
        b[kk][n] = *(const short8*)(Bh + (rB0 + n * 16 + lr) * 128 + (ub << 4));
    }
    if (t + 1 < 8) stgA(d ^ 1, 1, t + 1);
    __builtin_amdgcn_sched_barrier(0);
    __builtin_amdgcn_s_barrier();
    asm volatile("s_waitcnt lgkmcnt(0)" ::: "memory");
    __builtin_amdgcn_sched_barrier(0);
    __builtin_amdgcn_s_setprio(1);
#pragma unroll
    for (int kk = 0; kk < 2; kk++)
#pragma unroll
      for (int m = 0; m < 4; m++)
#pragma unroll
        for (int n = 0; n < 2; n++)
          acc[m][n] = __builtin_amdgcn_mfma_f32_16x16x32_bf16(a[kk][m], b[kk][n], acc[m][n], 0, 0, 0);
    __builtin_amdgcn_s_setprio(0);
    __builtin_amdgcn_sched_barrier(0);
    __builtin_amdgcn_s_barrier();
    __builtin_amdgcn_sched_barrier(0);

    // ---- P2 ----------------------------------------------------------------
#pragma unroll
    for (int kk = 0; kk < 2; kk++) {
      const int ub = ((kk << 2) + lk) ^ lr7;
#pragma unroll
      for (int n = 2; n < 4; n++)
        b[kk][n] = *(const short8*)(Bh + (rB0 + n * 16 + lr) * 128 + (ub << 4));
    }
    if (t + 1 < 8) stgB(d ^ 1, 1, t + 1);
    __builtin_amdgcn_sched_barrier(0);
    __builtin_amdgcn_s_barrier();
    asm volatile("s_waitcnt lgkmcnt(0)" ::: "memory");
    __builtin_amdgcn_sched_barrier(0);
    __builtin_amdgcn_s_setprio(1);
#pragma unroll
    for (int kk = 0; kk < 2; kk++)
#pragma unroll
      for (int m = 0; m < 4; m++)
#pragma unroll
        for (int n = 2; n < 4; n++)
          acc[m][n] = __builtin_amdgcn_mfma_f32_16x16x32_bf16(a[kk][m], b[kk][n], acc[m][n], 0, 0, 0);
    __builtin_amdgcn_s_setprio(0);
    __builtin_amdgcn_sched_barrier(0);
    __builtin_amdgcn_s_barrier();
    __builtin_amdgcn_sched_barrier(0);

    // ---- P3 ----------------------------------------------------------------
#pragma unroll
    for (int kk = 0; kk < 2; kk++) {
      const int ub = ((kk << 2) + lk) ^ lr7;
#pragma unroll
      for (int m = 0; m < 4; m++)
        a[kk][m] = *(const short8*)(Ah + (64 + m * 16 + lr) * 128 + (ub << 4));
    }
    if (t + 2 < 8) stgB(d, 0, t + 2);
    __builtin_amdgcn_sched_barrier(0);
    __builtin_amdgcn_s_barrier();
    asm volatile("s_waitcnt lgkmcnt(0)" ::: "memory");
    __builtin_amdgcn_sched_barrier(0);
    __builtin_amdgcn_s_setprio(1);
#pragma unroll
    for (int kk = 0; kk < 2; kk++)
#pragma unroll
      for (int m = 0; m < 4; m++)
#pragma unroll
        for (int n = 0; n < 2; n++)
          acc[m + 4][n] = __builtin_amdgcn_mfma_f32_16x16x32_bf16(a[kk][m], b[kk][n], acc[m + 4][n], 0, 0, 0);
    __builtin_amdgcn_s_setprio(0);
    __builtin_amdgcn_sched_barrier(0);
    __builtin_amdgcn_s_barrier();
    __builtin_amdgcn_sched_barrier(0);

    // ---- P4 ----------------------------------------------------------------
    if (t + 2 < 8) stgA(d, 0, t + 2);
    __builtin_amdgcn_sched_barrier(0);
    __builtin_amdgcn_s_setprio(1);
#pragma unroll
    for (int kk = 0; kk < 2; kk++)
#pragma unroll
      for (int m = 0; m < 4; m++)
#pragma unroll
        for (int n = 2; n < 4; n++)
          acc[m + 4][n] = __builtin_amdgcn_mfma_f32_16x16x32_bf16(a[kk][m], b[kk][n], acc[m + 4][n], 0, 0, 0);
    __builtin_amdgcn_s_setprio(0);
    __builtin_amdgcn_sched_barrier(0);
    if (t + 2 < 8) {
      asm volatile("s_waitcnt vmcnt(4)" ::: "memory");  // tile t+1 landed
    } else {
      asm volatile("s_waitcnt vmcnt(0)" ::: "memory");
    }
    __builtin_amdgcn_sched_barrier(0);
    __builtin_amdgcn_s_barrier();
    __builtin_amdgcn_sched_barrier(0);
  }

  // Epilogue: C/D layout col=lane&15, row=(lane>>4)*4+reg [m89]
#pragma unroll
  for (int m = 0; m < 8; m++) {
#pragma unroll
    for (int q = 0; q < 4; q++) {
      size_t grow = rowBase + wm * 128 + m * 16 + lk * 4 + q;
      int nsp = (int)(grow & 1023);
      int ii = nsp >> 5, jj = nsp & 31;
      float degf = (float)(1 + (ii > 0) + (ii < 31) + (jj > 0) + (jj < 31));
      const float* b2 = bias2 + (grow >> 10) * CTXD;
#pragma unroll
      for (int n = 0; n < 4; n++) {
        int gcol = colBase + wn * 64 + n * 16 + lr;
        float v = acc[m][n][q] + degf * b2[gcol];
        if constexpr (MODE == 1) {
          ((unsigned short*)Cp)[grow * CTXD + gcol] = f2bf(elu1(v));
        } else {
          ((float*)Cp)[grow * CTXD + gcol] = v;
        }
      }
    }
  }
}

// ---------------------------------------------------------------------------
extern "C" void kernel_launch(void* const* d_in, const int* in_sizes, int n_in,
                              void* d_out, int out_size, void* d_ws, size_t ws_size,
                              hipStream_t stream) {
  const float* images   = (const float*)d_in[0];
  const float* q_enc    = (const float*)d_in[1];
  const float* lstm     = (const float*)d_in[2];
  const int*   q_len    = (const int*)d_in[3];
  // d_in[4] = adj: implied by the 32x32 grid stencil, not read
  const float* initKB_w = (const float*)d_in[5];
  const float* initKB_b = (const float*)d_in[6];
  const float* W_w      = (const float*)d_in[7];
  const float* W_b      = (const float*)d_in[8];
  const float* qInput_w = (const float*)d_in[9];
  const float* qInput_b = (const float*)d_in[10];
  const float* qT_w     = (const float*)d_in[11];
  const float* qT_b     = (const float*)d_in[12];
  const float* cmd_w    = (const float*)d_in[13];
  const float* cmd_b    = (const float*)d_in[14];

  // ws layout:
  //   y (bf16 stencil out) : 64 MB  (transposed cmd weights aliased at front
  //        6 MB — consumed by q1_k/cmdt_k before first stencil_k writes y)
  //   kb_bf / w1_bf / bias2 / q1 after
  char* ws = (char*)d_ws;
  unsigned short* y     = (unsigned short*)ws;
  float*          qiT   = (float*)ws;                    // 1 MB
  float*          qTT   = (float*)(ws + 1048576);        // 4 MB
  float*          w2T   = (float*)(ws + 5242880);        // 1 MB
  unsigned short* kb_bf = (unsigned short*)(ws + 67108864);
  unsigned short* w1_bf = (unsigned short*)(ws + 68157440);
  float*          bias2 = (float*)(ws + 68681728);
  float*          q1    = (float*)(ws + 69206016);
  unsigned short* xloc  = (unsigned short*)d_out;        // bf16 half of d_out

  pack_k<<<9216, 256, 0, stream>>>(initKB_w, W_w, qInput_w, qT_w,
                                   kb_bf, w1_bf, qiT, qTT, w2T);
  q1_k<<<64, 512, 0, stream>>>(q_enc, qiT, qInput_b, q1);
  cmdt_k<<<256, 512, 0, stream>>>(q1, lstm, q_len, qTT, qT_b, cmd_w, cmd_b,
                                  w2T, W_b, bias2);

  // x_loc = images @ initKB_w^T + initKB_b  -> xloc (d_out bf16)
  igemm<<<2048, 256, 0, stream>>>(images, kb_bf, initKB_b, xloc);

  for (int t = 0; t < 4; t++) {
    stencil_k<<<16384, 256, 0, stream>>>(xloc, y);
    if (t < 3)
      gemm8<1><<<512, 512, 0, stream>>>(y, w1_bf, bias2 + (size_t)t * 32768, xloc);
    else
      gemm8<2><<<512, 512, 0, stream>>>(y, w1_bf, bias2 + (size_t)t * 32768, d_out);
  }
}

// Round 16
// 523.614 us; speedup vs baseline: 1.2376x; 1.0043x over previous
//
#include <hip/hip_runtime.h>
#include <hip/hip_bf16.h>
#include <math.h>

// SpatialGNN: B=64, N=1024 (32x32 grid), D_FEAT=1024, CTX=512, S=32, T=4
#define NB 64
#define NNODES 1024
#define CTXD 512
#define SEQL 32

typedef __attribute__((ext_vector_type(8))) short short8;
typedef __attribute__((ext_vector_type(4))) float floatx4;

__device__ __forceinline__ float bf2f(unsigned short u) {
  union { unsigned int i; float f; } v; v.i = ((unsigned int)u) << 16; return v.f;
}
__device__ __forceinline__ unsigned short f2bf(float f) {
  union { float f; unsigned int i; } v; v.f = f;
  unsigned int r = v.i + 0x7fffu + ((v.i >> 16) & 1u);  // RNE
  return (unsigned short)(r >> 16);
}
__device__ __forceinline__ float elu1(float x) { return x > 0.f ? x : expm1f(x); }

__device__ __forceinline__ void gload16(const void* g, void* l) {
  __builtin_amdgcn_global_load_lds((const __attribute__((address_space(1))) void*)g,
                                   (__attribute__((address_space(3))) void*)l, 16, 0, 0);
}

// ---------------------------------------------------------------------------
// Pack: bf16 GEMM weights + f32 TRANSPOSED cmd-path weights.
// ---------------------------------------------------------------------------
__global__ __launch_bounds__(256) void pack_k(const float* __restrict__ kbw,
                                              const float* __restrict__ Ww,
                                              const float* __restrict__ qiw,
                                              const float* __restrict__ qtw,
                                              unsigned short* __restrict__ kb_bf,
                                              unsigned short* __restrict__ w1_bf,
                                              float* __restrict__ qiT,
                                              float* __restrict__ qTT,
                                              float* __restrict__ w2T) {
  int idx = blockIdx.x * 256 + threadIdx.x;
  if (idx < 524288) {
    kb_bf[idx] = f2bf(kbw[idx]);
  } else if (idx < 786432) {
    int o = idx - 524288;
    w1_bf[o] = f2bf(Ww[(o >> 9) * 1024 + (o & 511)]);
  } else if (idx < 1048576) {
    int o = idx - 786432;
    int k = o >> 9, c = o & 511;
    qiT[o] = qiw[c * 512 + k];
  } else if (idx < 2097152) {
    int o = idx - 1048576;
    int t = o >> 18, r = o & 262143;
    int k = r >> 9, c = r & 511;
    qTT[o] = qtw[((size_t)t * 512 + c) * 512 + k];
  } else {
    int o = idx - 2097152;
    int k = o >> 9, c = o & 511;
    w2T[o] = Ww[c * 1024 + 512 + k];
  }
}

// ---------------------------------------------------------------------------
// q1[b][c] = elu(q_enc[b] @ qInput_w^T + qInput_b)
// ---------------------------------------------------------------------------
__global__ __launch_bounds__(512) void q1_k(const float* __restrict__ q_enc,
                                            const float* __restrict__ qiT,
                                            const float* __restrict__ qInput_b,
                                            float* __restrict__ q1) {
  int b = blockIdx.x, c = threadIdx.x;
  __shared__ float qes[512];
  qes[c] = q_enc[b * 512 + c];
  __syncthreads();
  float a0 = qInput_b[c], a1 = 0.f, a2 = 0.f, a3 = 0.f;
#pragma unroll 4
  for (int k = 0; k < 512; k += 4) {
    a0 += qes[k] * qiT[k * 512 + c];
    a1 += qes[k + 1] * qiT[(k + 1) * 512 + c];
    a2 += qes[k + 2] * qiT[(k + 2) * 512 + c];
    a3 += qes[k + 3] * qiT[(k + 3) * 512 + c];
  }
  q1[b * 512 + c] = elu1(a0 + a1 + a2 + a3);
}

// ---------------------------------------------------------------------------
// Per (t,b): q_cmd -> raw_att -> softmax -> cmd -> bias2[t][b][:]
// ---------------------------------------------------------------------------
__global__ __launch_bounds__(512) void cmdt_k(
    const float* __restrict__ q1, const float* __restrict__ lstm,
    const int* __restrict__ q_len,
    const float* __restrict__ qTT, const float* __restrict__ qT_b,
    const float* __restrict__ cmd_w, const float* __restrict__ cmd_b,
    const float* __restrict__ w2T, const float* __restrict__ W_b,
    float* __restrict__ bias2) {
  int b = blockIdx.x & 63;
  int t = blockIdx.x >> 6;
  int c = threadIdx.x;
  __shared__ float q1s[512];
  __shared__ float us[512];
  __shared__ float red[512];
  __shared__ float atts[32];
  __shared__ float cmds[512];

  q1s[c] = q1[b * 512 + c];
  __syncthreads();

  const float* wt = qTT + (size_t)t * 262144;
  float a0 = qT_b[t * 512 + c], a1 = 0.f, a2 = 0.f, a3 = 0.f;
#pragma unroll 4
  for (int k = 0; k < 512; k += 4) {
    a0 += q1s[k] * wt[k * 512 + c];
    a1 += q1s[k + 1] * wt[(k + 1) * 512 + c];
    a2 += q1s[k + 2] * wt[(k + 2) * 512 + c];
    a3 += q1s[k + 3] * wt[(k + 3) * 512 + c];
  }
  us[c] = (a0 + a1 + a2 + a3) * cmd_w[c];
  __syncthreads();

  const float* lstmb = lstm + (size_t)b * SEQL * 512;
  {
    int s = c >> 4, u = c & 15;
    float p = 0.f;
    const float* lr = lstmb + s * 512;
    for (int r = u; r < 512; r += 16) p += us[r] * lr[r];
    red[c] = p;
  }
  __syncthreads();
  if (c < 32) {
    float raw = cmd_b[0];
    for (int u = 0; u < 16; u++) raw += red[c * 16 + u];
    raw = (c < q_len[b]) ? raw : -1e30f;
    float mx = raw;
    for (int off = 16; off; off >>= 1) mx = fmaxf(mx, __shfl_xor(mx, off, 32));
    float e = expf(raw - mx);
    float sm = e;
    for (int off = 16; off; off >>= 1) sm += __shfl_xor(sm, off, 32);
    atts[c] = e / sm;
  }
  __syncthreads();
  float cd = 0.f;
#pragma unroll
  for (int s = 0; s < 32; s++) cd += atts[s] * lstmb[s * 512 + c];
  cmds[c] = cd;
  __syncthreads();

  float b0 = W_b[c], b1 = 0.f, b2 = 0.f, b3 = 0.f;
#pragma unroll 4
  for (int k = 0; k < 512; k += 4) {
    b0 += cmds[k] * w2T[k * 512 + c];
    b1 += cmds[k + 1] * w2T[(k + 1) * 512 + c];
    b2 += cmds[k + 2] * w2T[(k + 2) * 512 + c];
    b3 += cmds[k + 3] * w2T[(k + 3) * 512 + c];
  }
  bias2[((size_t)(t * 64 + b)) * 512 + c] = b0 + b1 + b2 + b3;
}

// ---------------------------------------------------------------------------
// 5-point stencil: y[b,n,:] = sum_{m in nbr(n)} x[b,m,:]   (bf16, f32 sum)
// ---------------------------------------------------------------------------
__global__ __launch_bounds__(256) void stencil_k(const unsigned short* __restrict__ x,
                                                 unsigned short* __restrict__ y) {
  int g = blockIdx.x * 256 + threadIdx.x;
  int v = g & 63;
  int n = (g >> 6) & 1023;
  int b = g >> 16;
  size_t base = ((((size_t)b << 10) + n) << 9) + v * 8;
  const unsigned short* p = x + base;
  float acc[8];
  short8 s = *(const short8*)p;
#pragma unroll
  for (int j = 0; j < 8; j++) acc[j] = bf2f((unsigned short)s[j]);
  int i = n >> 5, jj = n & 31;
  if (i > 0) {
    short8 t = *(const short8*)(p - 32 * 512);
#pragma unroll
    for (int j = 0; j < 8; j++) acc[j] += bf2f((unsigned short)t[j]);
  }
  if (i < 31) {
    short8 t = *(const short8*)(p + 32 * 512);
#pragma unroll
    for (int j = 0; j < 8; j++) acc[j] += bf2f((unsigned short)t[j]);
  }
  if (jj > 0) {
    short8 t = *(const short8*)(p - 512);
#pragma unroll
    for (int j = 0; j < 8; j++) acc[j] += bf2f((unsigned short)t[j]);
  }
  if (jj < 31) {
    short8 t = *(const short8*)(p + 512);
#pragma unroll
    for (int j = 0; j < 8; j++) acc[j] += bf2f((unsigned short)t[j]);
  }
  short8 o;
#pragma unroll
  for (int j = 0; j < 8; j++) o[j] = (short)f2bf(acc[j]);
  *(short8*)(y + base) = o;
}

// ---------------------------------------------------------------------------
// Init GEMM, 64x512 tile (FULL N): 4 waves, each 64x128 out (acc[4][8]),
// BK=64, K=1024. A f32 reg-staged+cvt (2 loads/thread), B = full 512 rows
// staged/step (16 gload16/thread, 64 KB). LDS 72 KB -> 2 blocks/CU (8
// waves/CU, same as round-9's 3x smaller tile) but 64 MFMA per barrier-pair
// (2x) and 25% fewer LDS reads per MFMA. Proven XOR swizzle throughout.
// ---------------------------------------------------------------------------
__global__ __launch_bounds__(256, 2) void igemm(
    const float* __restrict__ Af,
    const unsigned short* __restrict__ Bw,
    const float* __restrict__ cbias,
    unsigned short* __restrict__ Cp) {
  __shared__ __align__(128) unsigned short As[64 * 64];    //  8 KB
  __shared__ __align__(128) unsigned short Bs[512 * 64];   // 64 KB

  const int tid = threadIdx.x;
  const int lane = tid & 63;
  const int wn = tid >> 6;          // wave = 128-col slice, 0..3
  const int lr = lane & 15;
  const int lk = lane >> 4;
  const int lr7 = lr & 7;

  // XCD-aware bijective swizzle (grid = 1024, divisible by 8)
  int bid = blockIdx.x;
  int wg = (bid & 7) * (gridDim.x >> 3) + (bid >> 3);
  const size_t rowBase = (size_t)wg * 64;

  floatx4 acc[4][8];
#pragma unroll
  for (int m = 0; m < 4; m++)
#pragma unroll
    for (int n = 0; n < 8; n++) acc[m][n] = {0.f, 0.f, 0.f, 0.f};

  for (int k0 = 0; k0 < 1024; k0 += 64) {
    __syncthreads();
    // A: f32 reg-stage + cvt, swizzled ds_write (2 granules/thread)
#pragma unroll
    for (int j = 0; j < 2; j++) {
      int g = j * 256 + tid;
      int r = g >> 3, u = g & 7;
      const float* src = Af + (rowBase + r) * (size_t)1024 + k0 + u * 8;
      floatx4 v0 = *(const floatx4*)src;
      floatx4 v1 = *(const floatx4*)(src + 4);
      short8 t;
#pragma unroll
      for (int e = 0; e < 4; e++) {
        t[e] = (short)f2bf(v0[e]);
        t[e + 4] = (short)f2bf(v1[e]);
      }
      *(short8*)((char*)As + r * 128 + ((u ^ (r & 7)) << 4)) = t;
    }
    // B: full 512 rows, 16 gload16/thread, pre-swizzled source
#pragma unroll
    for (int j = 0; j < 16; j++) {
      int g = j * 256 + tid;
      int r = g >> 3, u = g & 7;
      gload16(Bw + (size_t)r * 1024 + k0 + ((u ^ (r & 7)) << 3),
              (char*)Bs + g * 16);
    }
    __syncthreads();

#pragma unroll
    for (int kk = 0; kk < 2; kk++) {
      const int ub = ((kk << 2) + lk) ^ lr7;
      short8 a[4], b[8];
#pragma unroll
      for (int m = 0; m < 4; m++)
        a[m] = *(const short8*)((const char*)As + (m * 16 + lr) * 128 + (ub << 4));
#pragma unroll
      for (int n = 0; n < 8; n++)
        b[n] = *(const short8*)((const char*)Bs + (wn * 128 + n * 16 + lr) * 128 + (ub << 4));
#pragma unroll
      for (int m = 0; m < 4; m++)
#pragma unroll
        for (int n = 0; n < 8; n++)
          acc[m][n] = __builtin_amdgcn_mfma_f32_16x16x32_bf16(a[m], b[n], acc[m][n], 0, 0, 0);
    }
  }

  // Epilogue: C/D layout col=lane&15, row=(lane>>4)*4+reg [m89]
#pragma unroll
  for (int m = 0; m < 4; m++) {
#pragma unroll
    for (int q = 0; q < 4; q++) {
      size_t grow = rowBase + m * 16 + lk * 4 + q;
#pragma unroll
      for (int n = 0; n < 8; n++) {
        int gcol = wn * 128 + n * 16 + lr;
        Cp[grow * CTXD + gcol] = f2bf(acc[m][n][q] + cbias[gcol]);
      }
    }
  }
}

// ---------------------------------------------------------------------------
// Loop GEMM, 8-phase counted-vmcnt schedule (round-9 proven, unchanged):
// 256x256 tile, 8 waves (2M x 4N, wave out 128x64), BK=64, K=512 (NT=8).
// MODE 1: +deg*bias2, elu, bf16 out.  MODE 2: +deg*bias2, no act, f32 out.
// ---------------------------------------------------------------------------
template <int MODE>
__global__ __launch_bounds__(512, 2) void gemm8(
    const unsigned short* __restrict__ Ay,
    const unsigned short* __restrict__ Bw,
    const float* __restrict__ bias2,
    void* __restrict__ Cp) {
  __shared__ __align__(128) unsigned short AsL[2][2][8192];  // 64 KB
  __shared__ __align__(128) unsigned short BsL[2][2][8192];  // 64 KB

  const int tid = threadIdx.x;
  const int lane = tid & 63;
  const int wave = tid >> 6;       // 0..7
  const int wm = wave >> 2;        // 0..1  -> A half = wm
  const int wn = wave & 3;         // 0..3  -> B half = wn>>1
  const int lr = lane & 15;
  const int lk = lane >> 4;
  const int lr7 = lr & 7;
  const int rB0 = (wn & 1) * 64;

  int bid = blockIdx.x;
  int wg = (bid & 7) * (gridDim.x >> 3) + (bid >> 3);   // grid=512, %8==0
  const size_t rowBase = (size_t)(wg >> 1) * 256;
  const int colBase = (wg & 1) * 256;

  floatx4 acc[8][4];
#pragma unroll
  for (int m = 0; m < 8; m++)
#pragma unroll
    for (int n = 0; n < 4; n++) acc[m][n] = {0.f, 0.f, 0.f, 0.f};

  auto stgA = [&](int d, int h, int kt) {
#pragma unroll
    for (int j = 0; j < 2; j++) {
      int g = j * 512 + tid, r = g >> 3, u = g & 7;
      gload16(Ay + (rowBase + h * 128 + r) * (size_t)512 + kt * 64 + ((u ^ (r & 7)) << 3),
              (char*)&AsL[d][h][0] + g * 16);
    }
  };
  auto stgB = [&](int d, int h, int kt) {
#pragma unroll
    for (int j = 0; j < 2; j++) {
      int g = j * 512 + tid, r = g >> 3, u = g & 7;
      gload16(Bw + (size_t)(colBase + h * 128 + r) * 512 + kt * 64 + ((u ^ (r & 7)) << 3),
              (char*)&BsL[d][h][0] + g * 16);
    }
  };

  // prologue
  stgB(0, 0, 0); stgA(0, 0, 0); stgA(0, 1, 0); stgB(0, 1, 0);
  stgB(1, 0, 1); stgA(1, 0, 1);
  asm volatile("s_waitcnt vmcnt(4)" ::: "memory");  // tile 0 landed
  __builtin_amdgcn_sched_barrier(0);
  __builtin_amdgcn_s_barrier();
  __builtin_amdgcn_sched_barrier(0);

  short8 a[2][4], b[2][4];

  for (int t = 0; t < 8; t++) {
    const int d = t & 1;
    const char* Ah = (const char*)&AsL[d][wm][0];
    const char* Bh = (const char*)&BsL[d][wn >> 1][0];

    // ---- P1 ----------------------------------------------------------------
#pragma unroll
    for (int kk = 0; kk < 2; kk++) {
      const int ub = ((kk << 2) + lk) ^ lr7;
#pragma unroll
      for (int m = 0; m < 4; m++)
        a[kk][m] = *(const short8*)(Ah + (m * 16 + lr) * 128 + (ub << 4));
#pragma unroll
      for (int n = 0; n < 2; n++)
        b[kk][n] = *(const short8*)(Bh + (rB0 + n * 16 + lr) * 128 + (ub << 4));
    }
    if (t + 1 < 8) stgA(d ^ 1, 1, t + 1);
    __builtin_amdgcn_sched_barrier(0);
    __builtin_amdgcn_s_barrier();
    asm volatile("s_waitcnt lgkmcnt(0)" ::: "memory");
    __builtin_amdgcn_sched_barrier(0);
    __builtin_amdgcn_s_setprio(1);
#pragma unroll
    for (int kk = 0; kk < 2; kk++)
#pragma unroll
      for (int m = 0; m < 4; m++)
#pragma unroll
        for (int n = 0; n < 2; n++)
          acc[m][n] = __builtin_amdgcn_mfma_f32_16x16x32_bf16(a[kk][m], b[kk][n], acc[m][n], 0, 0, 0);
    __builtin_amdgcn_s_setprio(0);
    __builtin_amdgcn_sched_barrier(0);
    __builtin_amdgcn_s_barrier();
    __builtin_amdgcn_sched_barrier(0);

    // ---- P2 ----------------------------------------------------------------
#pragma unroll
    for (int kk = 0; kk < 2; kk++) {
      const int ub = ((kk << 2) + lk) ^ lr7;
#pragma unroll
      for (int n = 2; n < 4; n++)
        b[kk][n] = *(const short8*)(Bh + (rB0 + n * 16 + lr) * 128 + (ub << 4));
    }
    if (t + 1 < 8) stgB(d ^ 1, 1, t + 1);
    __builtin_amdgcn_sched_barrier(0);
    __builtin_amdgcn_s_barrier();
    asm volatile("s_waitcnt lgkmcnt(0)" ::: "memory");
    __builtin_amdgcn_sched_barrier(0);
    __builtin_amdgcn_s_setprio(1);
#pragma unroll
    for (int kk = 0; kk < 2; kk++)
#pragma unroll
      for (int m = 0; m < 4; m++)
#pragma unroll
        for (int n = 2; n < 4; n++)
          acc[m][n] = __builtin_amdgcn_mfma_f32_16x16x32_bf16(a[kk][m], b[kk][n], acc[m][n], 0, 0, 0);
    __builtin_amdgcn_s_setprio(0);
    __builtin_amdgcn_sched_barrier(0);
    __builtin_amdgcn_s_barrier();
    __builtin_amdgcn_sched_barrier(0);

    // ---- P3 ----------------------------------------------------------------
#pragma unroll
    for (int kk = 0; kk < 2; kk++) {
      const int ub = ((kk << 2) + lk) ^ lr7;
#pragma unroll
      for (int m = 0; m < 4; m++)
        a[kk][m] = *(const short8*)(Ah + (64 + m * 16 + lr) * 128 + (ub << 4));
    }
    if (t + 2 < 8) stgB(d, 0, t + 2);
    __builtin_amdgcn_sched_barrier(0);
    __builtin_amdgcn_s_barrier();
    asm volatile("s_waitcnt lgkmcnt(0)" ::: "memory");
    __builtin_amdgcn_sched_barrier(0);
    __builtin_amdgcn_s_setprio(1);
#pragma unroll
    for (int kk = 0; kk < 2; kk++)
#pragma unroll
      for (int m = 0; m < 4; m++)
#pragma unroll
        for (int n = 0; n < 2; n++)
          acc[m + 4][n] = __builtin_amdgcn_mfma_f32_16x16x32_bf16(a[kk][m], b[kk][n], acc[m + 4][n], 0, 0, 0);
    __builtin_amdgcn_s_setprio(0);
    __builtin_amdgcn_sched_barrier(0);
    __builtin_amdgcn_s_barrier();
    __builtin_amdgcn_sched_barrier(0);

    // ---- P4 ----------------------------------------------------------------
    if (t + 2 < 8) stgA(d, 0, t + 2);
    __builtin_amdgcn_sched_barrier(0);
    __builtin_amdgcn_s_setprio(1);
#pragma unroll
    for (int kk = 0; kk < 2; kk++)
#pragma unroll
      for (int m = 0; m < 4; m++)
#pragma unroll
        for (int n = 2; n < 4; n++)
          acc[m + 4][n] = __builtin_amdgcn_mfma_f32_16x16x32_bf16(a[kk][m], b[kk][n], acc[m + 4][n], 0, 0, 0);
    __builtin_amdgcn_s_setprio(0);
    __builtin_amdgcn_sched_barrier(0);
    if (t + 2 < 8) {
      asm volatile("s_waitcnt vmcnt(4)" ::: "memory");  // tile t+1 landed
    } else {
      asm volatile("s_waitcnt vmcnt(0)" ::: "memory");
    }
    __builtin_amdgcn_sched_barrier(0);
    __builtin_amdgcn_s_barrier();
    __builtin_amdgcn_sched_barrier(0);
  }

  // Epilogue: C/D layout col=lane&15, row=(lane>>4)*4+reg [m89]
#pragma unroll
  for (int m = 0; m < 8; m++) {
#pragma unroll
    for (int q = 0; q < 4; q++) {
      size_t grow = rowBase + wm * 128 + m * 16 + lk * 4 + q;
      int nsp = (int)(grow & 1023);
      int ii = nsp >> 5, jj = nsp & 31;
      float degf = (float)(1 + (ii > 0) + (ii < 31) + (jj > 0) + (jj < 31));
      const float* b2 = bias2 + (grow >> 10) * CTXD;
#pragma unroll
      for (int n = 0; n < 4; n++) {
        int gcol = colBase + wn * 64 + n * 16 + lr;
        float v = acc[m][n][q] + degf * b2[gcol];
        if constexpr (MODE == 1) {
          ((unsigned short*)Cp)[grow * CTXD + gcol] = f2bf(elu1(v));
        } else {
          ((float*)Cp)[grow * CTXD + gcol] = v;
        }
      }
    }
  }
}

// ---------------------------------------------------------------------------
extern "C" void kernel_launch(void* const* d_in, const int* in_sizes, int n_in,
                              void* d_out, int out_size, void* d_ws, size_t ws_size,
                              hipStream_t stream) {
  const float* images   = (const float*)d_in[0];
  const float* q_enc    = (const float*)d_in[1];
  const float* lstm     = (const float*)d_in[2];
  const int*   q_len    = (const int*)d_in[3];
  // d_in[4] = adj: implied by the 32x32 grid stencil, not read
  const float* initKB_w = (const float*)d_in[5];
  const float* initKB_b = (const float*)d_in[6];
  const float* W_w      = (const float*)d_in[7];
  const float* W_b      = (const float*)d_in[8];
  const float* qInput_w = (const float*)d_in[9];
  const float* qInput_b = (const float*)d_in[10];
  const float* qT_w     = (const float*)d_in[11];
  const float* qT_b     = (const float*)d_in[12];
  const float* cmd_w    = (const float*)d_in[13];
  const float* cmd_b    = (const float*)d_in[14];

  // ws layout:
  //   y (bf16 stencil out) : 64 MB  (transposed cmd weights aliased at front
  //        6 MB — consumed by q1_k/cmdt_k before first stencil_k writes y)
  //   kb_bf / w1_bf / bias2 / q1 after
  char* ws = (char*)d_ws;
  unsigned short* y     = (unsigned short*)ws;
  float*          qiT   = (float*)ws;                    // 1 MB
  float*          qTT   = (float*)(ws + 1048576);        // 4 MB
  float*          w2T   = (float*)(ws + 5242880);        // 1 MB
  unsigned short* kb_bf = (unsigned short*)(ws + 67108864);
  unsigned short* w1_bf = (unsigned short*)(ws + 68157440);
  float*          bias2 = (float*)(ws + 68681728);
  float*          q1    = (float*)(ws + 69206016);
  unsigned short* xloc  = (unsigned short*)d_out;        // bf16 half of d_out

  pack_k<<<9216, 256, 0, stream>>>(initKB_w, W_w, qInput_w, qT_w,
                                   kb_bf, w1_bf, qiT, qTT, w2T);
  q1_k<<<64, 512, 0, stream>>>(q_enc, qiT, qInput_b, q1);
  cmdt_k<<<256, 512, 0, stream>>>(q1, lstm, q_len, qTT, qT_b, cmd_w, cmd_b,
                                  w2T, W_b, bias2);

  // x_loc = images @ initKB_w^T + initKB_b  -> xloc (d_out bf16)
  igemm<<<1024, 256, 0, stream>>>(images, kb_bf, initKB_b, xloc);

  for (int t = 0; t < 4; t++) {
    stencil_k<<<16384, 256, 0, stream>>>(xloc, y);
    if (t < 3)
      gemm8<1><<<512, 512, 0, stream>>>(y, w1_bf, bias2 + (size_t)t * 32768, xloc);
    else
      gemm8<2><<<512, 512, 0, stream>>>(y, w1_bf, bias2 + (size_t)t * 32768, d_out);
  }
}